// Round 5
// baseline (146.428 us; speedup 1.0000x reference)
//
#include <hip/hip_runtime.h>

#define TT 50
#define START_TAG 48
#define STOP_TAG 49
#define BB 1024
#define LL 512

// Rescale: multiply by 2^±64, offset 64*ln2. Checked every 2 steps:
// worst growth ~2^20/step => from <=2^63 reaches <=2^103 < 2^128. Safe.
#define UP_THR   0x1p63f
#define DOWN_THR 0x1p-32f
#define OFF_64LN2 44.3614195558364998f

#define RING 8
#define PF   8

typedef __attribute__((address_space(3))) uint32_t lds_u32_t;
typedef __attribute__((address_space(1))) const uint32_t glb_u32_t;

__device__ __forceinline__ void load_lds4(const float* g, float* l) {
    // LDS dest = uniform base + lane*4 ; global src per-lane
    __builtin_amdgcn_global_load_lds((glb_u32_t*)g, (lds_u32_t*)l, 4, 0, 0);
}

// One chain (fwd or bwd half of one sequence), one wave, lane = tag.
// fwd: e' = (M @ e) * elg_t        M[i][j] = exp(trans[i][j])
// bwd: e' = M^T @ (e * elg_t)
// e-broadcast via LDS same-address float4 reads (HW broadcast).
template<bool BWD>
__device__ __forceinline__ void run_chain(
    int b, int lane, int len,
    const float* __restrict__ logits, const float* __restrict__ trans,
    float (*ring)[64], float* __restrict__ bc,
    float& e_out, float& moff_out)
{
    const int mid    = len >> 1;
    const int nsteps = BWD ? (len - mid) : mid;

    // M fragment: fwd Mf[p][q] = exp(trans[lane][4p+q]); bwd exp(trans[4p+q][lane]).
    // Rows/cols >= TT zero (kills pad lanes and pad bc entries).
    float4 Mf[13];
    {
        const int lc = (lane < TT) ? lane : 0;
#pragma unroll
        for (int p = 0; p < 13; ++p) {
            float mv[4];
#pragma unroll
            for (int q = 0; q < 4; ++q) {
                const int j = 4 * p + q;
                float v = 0.0f;
                if (j < TT && lane < TT)
                    v = __expf(BWD ? trans[j * TT + lc] : trans[lc * TT + j]);
                mv[q] = v;
            }
            Mf[p] = make_float4(mv[0], mv[1], mv[2], mv[3]);
        }
    }

    float e = BWD ? ((lane < TT) ? __expf(trans[STOP_TAG * TT + lane]) : 0.0f)
                  : ((lane == START_TAG) ? 1.0f : 0.0f);
    float moff = 0.0f;

    if (nsteps > 0) {
        const int lane_c = (lane < TT) ? lane : (TT - 1);
        const float* gp = logits + (size_t)b * LL * TT + lane_c;

        // fill prefetch pipe (clamped indices)
#pragma unroll
        for (int i = 0; i < PF; ++i) {
            int kk = i; if (kk > nsteps - 1) kk = nsteps - 1;
            int t = BWD ? (len - 1 - kk) : kk;
            load_lds4(gp + (size_t)t * TT, &ring[i][0]);
        }
        asm volatile("s_waitcnt vmcnt(6)" ::: "memory");   // slots 0,1 in LDS
        __builtin_amdgcn_sched_barrier(0);
        float elg  = __expf(ring[0][lane]);
        float lgN1 = ring[1][lane];

        for (int k = 0; k < nsteps; ++k) {
            // issued = PF + k ; retire >= k+3 => slot k+2 in LDS
            asm volatile("s_waitcnt vmcnt(5)" ::: "memory");
            __builtin_amdgcn_sched_barrier(0);
            float lgN2 = ring[(k + 2) & (RING - 1)][lane];  // consumed next iter
            {
                int kk = k + PF; if (kk > nsteps - 1) kk = nsteps - 1;
                int t = BWD ? (len - 1 - kk) : kk;
                load_lds4(gp + (size_t)t * TT, &ring[(k + PF) & (RING - 1)][0]);
            }
            float elgN = __expf(lgN1);      // logit loaded 2 steps ago: off-chain

            bc[lane] = BWD ? (e * elg) : e; // ds_write; lanes>=50 write 0

            float4 acc = make_float4(0.f, 0.f, 0.f, 0.f);
#pragma unroll
            for (int p = 0; p < 13; ++p) {
                float4 f = *reinterpret_cast<const float4*>(&bc[4 * p]); // broadcast
                acc.x = fmaf(Mf[p].x, f.x, acc.x);
                acc.y = fmaf(Mf[p].y, f.y, acc.y);
                acc.z = fmaf(Mf[p].z, f.z, acc.z);
                acc.w = fmaf(Mf[p].w, f.w, acc.w);
            }
            float s  = (acc.x + acc.y) + (acc.z + acc.w);
            float en = BWD ? s : s * elg;   // pad lanes: Mf==0 -> s==0 -> en==0

            if (k & 1) {                    // exact power-of-two rescale, every 2
                if (__any(en > UP_THR))         { en *= 0x1p-64f; moff += OFF_64LN2; }
                else if (!__any(en > DOWN_THR)) { en *= 0x1p64f;  moff -= OFF_64LN2; }
            }
            e = en; elg = elgN; lgN1 = lgN2;
        }
    }

    // normalize (max -> 1)
    float mm = e;
#pragma unroll
    for (int o = 32; o > 0; o >>= 1) mm = fmaxf(mm, __shfl_xor(mm, o));
    e_out = e * (1.0f / mm);
    moff_out = moff + __logf(mm);
}

// ---------------- fused kernel: wave0 fwd, wave1 bwd, wave2 gold score ------
__global__ __launch_bounds__(192) void crf_main(
    const float* __restrict__ logits, const float* __restrict__ trans,
    const int* __restrict__ labels, const int* __restrict__ lens,
    float* __restrict__ nll)
{
    __shared__ __align__(16) float ringF[RING][64];
    __shared__ __align__(16) float ringB[RING][64];
    __shared__ __align__(16) float bcF[64];
    __shared__ __align__(16) float bcB[64];
    __shared__ __align__(16) float xchB[64];
    __shared__ float moffB_sh, score_sh;

    const int b    = blockIdx.x;
    const int wid  = threadIdx.x >> 6;
    const int lane = threadIdx.x & 63;
    const int len  = lens[b];

    float eF = 0.0f, moffF = 0.0f;

    if (wid == 0) {
        run_chain<false>(b, lane, len, logits, trans, ringF, bcF, eF, moffF);
    } else if (wid == 1) {
        float eB, moffB;
        run_chain<true>(b, lane, len, logits, trans, ringB, bcB, eB, moffB);
        xchB[lane] = eB;
        if (lane == 0) moffB_sh = moffB;
    } else {
        float acc = 0.0f;
        for (int t = lane; t < len; t += 64) {
            int lab = labels[b * LL + t];
            acc += logits[((size_t)b * LL + t) * TT + lab];
            int prev = (t == 0) ? START_TAG : labels[b * LL + t - 1];
            acc += trans[lab * TT + prev];
        }
        if (lane == 0) acc += trans[STOP_TAG * TT + labels[b * LL + (len - 1)]];
#pragma unroll
        for (int o = 32; o > 0; o >>= 1) acc += __shfl_xor(acc, o);
        if (lane == 0) score_sh = acc;
    }

    __syncthreads();

    if (wid == 0) {
        float p = eF * xchB[lane];
#pragma unroll
        for (int o = 32; o > 0; o >>= 1) p += __shfl_xor(p, o);
        if (lane == 0)
            nll[b] = (moffF + moffB_sh + __logf(p)) - score_sh;
    }
}

// ---------------- final deterministic reduction ------------------------------
__global__ __launch_bounds__(1024) void crf_reduce(
    const float* __restrict__ nll, float* __restrict__ out)
{
    __shared__ float red[16];
    const int tid = threadIdx.x;
    float acc = nll[tid];
#pragma unroll
    for (int o = 32; o > 0; o >>= 1) acc += __shfl_xor(acc, o);
    if ((tid & 63) == 0) red[tid >> 6] = acc;
    __syncthreads();
    if (tid == 0) {
        float tot = 0.0f;
        for (int i = 0; i < 16; ++i) tot += red[i];
        out[0] = tot / (float)BB;
    }
}

extern "C" void kernel_launch(void* const* d_in, const int* in_sizes, int n_in,
                              void* d_out, int out_size, void* d_ws, size_t ws_size,
                              hipStream_t stream) {
    const float* logits = (const float*)d_in[0];
    const float* trans  = (const float*)d_in[1];
    const int*   labels = (const int*)d_in[2];
    const int*   lens   = (const int*)d_in[3];

    float* nll = (float*)d_ws;              // [B]
    float* out = (float*)d_out;

    crf_main<<<BB, 192, 0, stream>>>(logits, trans, labels, lens, nll);
    crf_reduce<<<1, 1024, 0, stream>>>(nll, out);
}

// Round 6
// 134.563 us; speedup vs baseline: 1.0882x; 1.0882x over previous
//
#include <hip/hip_runtime.h>
#include <hip/hip_bf16.h>

#define TT 50
#define LL 512
#define BB 1024
#define START_TAG 48
#define STOP_TAG 49
#define RING 8
#define PFS 6                 // prologue slots staged ahead
#define LN2F 0.69314718056f
#define UP_THR 0x1p40f
#define DN_THR 0x1p-20f

typedef __attribute__((ext_vector_type(4))) short bf16x4;
typedef __attribute__((ext_vector_type(4))) float f32x4;

typedef __attribute__((address_space(3))) unsigned int lds_u32_t;
typedef __attribute__((address_space(1))) const unsigned int glb_u32_t;

__device__ __forceinline__ void load_lds4(const void* g, void* l) {
    __builtin_amdgcn_global_load_lds((glb_u32_t*)g, (lds_u32_t*)l, 4, 0, 0);
}

__device__ __forceinline__ f32x4 mfma16(bf16x4 a, bf16x4 b, f32x4 c) {
#if __has_builtin(__builtin_amdgcn_mfma_f32_16x16x16bf16_1k)
    return __builtin_amdgcn_mfma_f32_16x16x16bf16_1k(a, b, c, 0, 0, 0);
#else
    f32x4 d;
    asm("v_mfma_f32_16x16x16_bf16 %0, %1, %2, %3\n\ts_nop 7\n\ts_nop 1"
        : "=v"(d) : "v"(a), "v"(b), "v"(c));
    return d;
#endif
}

__device__ __forceinline__ unsigned int cvtpk(float lo, float hi) {
    unsigned int w;
    asm("v_cvt_pk_bf16_f32 %0, %1, %2" : "=v"(w) : "v"(lo), "v"(hi));
    return w;
}
__device__ __forceinline__ bf16x4 bits_to_bf(unsigned int lo, unsigned int hi) {
    union { unsigned int u[2]; bf16x4 v; } c; c.u[0] = lo; c.u[1] = hi; return c.v;
}
__device__ __forceinline__ bf16x4 make_bf4(float a, float b, float c, float d) {
    return bits_to_bf(cvtpk(a, b), cvtpk(c, d));
}

// ---------------- one direction's chain for a group of 16 sequences ----------
// fwd: e' = (M  e) ⊙ elg_t      M[i][j] = exp(trans[i][j]), state = e (x-form)
// bwd: x' = (M^T x) ⊙ elg_t'    x_a = elg_{len-1-a} ⊙ b_a
// State lives as 3 bf16x4 B-operand fragments (tags 0..47, col = seq).
template<bool BWD>
__device__ void run_chain(int g, int lane,
    const float* __restrict__ logits, const float* __restrict__ trans,
    const int* __restrict__ lens,
    float* __restrict__ vec_out, float* __restrict__ sc_out,
    float (&ring)[RING][12 * 64])
{
    const int col = lane & 15, grp = lane >> 4;
    const int b   = g * 16 + col;
    const int len = lens[b];
    const int mid = len >> 1;
    const int ns_eff = BWD ? (len - mid + 1) : mid;   // live iters: k < ns_eff

    int km = ns_eff;
#pragma unroll
    for (int o = 1; o < 64; o <<= 1) km = max(km, __shfl_xor(km, o));

    // M as 9 constant A-fragments: A[m=16T+col][k=16C+4*grp+j]
    bf16x4 A[3][3];
#pragma unroll
    for (int T = 0; T < 3; ++T)
#pragma unroll
        for (int C = 0; C < 3; ++C) {
            float v[4];
#pragma unroll
            for (int j = 0; j < 4; ++j) {
                const int m  = 16 * T + col;
                const int kk = 16 * C + 4 * grp + j;
                v[j] = __expf(BWD ? trans[kk * TT + m] : trans[m * TT + kk]);
            }
            A[T][C] = make_bf4(v[0], v[1], v[2], v[3]);
        }

    // staging: instr s, lane -> (seq = lane>>2, tag = 4s + (lane&3)); byte offsets
    const int sseq = lane >> 2;
    const int sb   = g * 16 + sseq;
    const int slen = lens[sb];
    int soff[12], smin[12];
#pragma unroll
    for (int s = 0; s < 12; ++s) {
        const int stag  = 4 * s + (lane & 3);
        const int base0 = (sb * LL * TT + stag) * 4;
        smin[s] = base0;
        soff[s] = BWD ? base0 + (slen - 1) * TT * 4 : base0;
    }
    const char* gbase = (const char*)logits;

    // prologue: stage slots 0..PFS-1
#pragma unroll
    for (int i = 0; i < PFS; ++i) {
#pragma unroll
        for (int s = 0; s < 12; ++s) {
            load_lds4(gbase + soff[s], &ring[i][s * 64]);
            soff[s] = BWD ? max(soff[s] - TT * 4, smin[s]) : soff[s] + TT * 4;
        }
    }
    asm volatile("s_waitcnt vmcnt(36)" ::: "memory");   // slots 0,1 resident
    __builtin_amdgcn_sched_barrier(0);

    // init state from slot0 logits
    f32x4 l0a = *(const f32x4*)(&ring[0][(0 * 4 + grp) * 64 + col * 4]);
    f32x4 l0b = *(const f32x4*)(&ring[0][(1 * 4 + grp) * 64 + col * 4]);
    f32x4 l0c = *(const f32x4*)(&ring[0][(2 * 4 + grp) * 64 + col * 4]);
    unsigned int st[6];
#pragma unroll
    for (int C = 0; C < 3; ++C) {
        const f32x4 lg = (C == 0) ? l0a : (C == 1) ? l0b : l0c;
        float v[4];
#pragma unroll
        for (int j = 0; j < 4; ++j) {
            const int tag = 16 * C + 4 * grp + j;
            const float tv = BWD ? trans[STOP_TAG * TT + tag]
                                 : trans[tag * TT + START_TAG];
            v[j] = __expf(tv) * __expf(lg[j]);
        }
        st[2 * C]     = cvtpk(v[0], v[1]);
        st[2 * C + 1] = cvtpk(v[2], v[3]);
    }

    // prep elg for iter 1 from slot1
    f32x4 e0, e1, e2;
    {
        f32x4 m0 = *(const f32x4*)(&ring[1][(0 * 4 + grp) * 64 + col * 4]);
        f32x4 m1 = *(const f32x4*)(&ring[1][(1 * 4 + grp) * 64 + col * 4]);
        f32x4 m2 = *(const f32x4*)(&ring[1][(2 * 4 + grp) * 64 + col * 4]);
#pragma unroll
        for (int j = 0; j < 4; ++j) { e0[j] = __expf(m0[j]); e1[j] = __expf(m1[j]); e2[j] = __expf(m2[j]); }
    }
    float shApp = 0.f, moff2 = 0.f;
    const f32x4 kZ = {0.f, 0.f, 0.f, 0.f};

    for (int k = 1; k < km; ++k) {
        asm volatile("s_waitcnt vmcnt(36)" ::: "memory");   // slot k+1 resident
        __builtin_amdgcn_sched_barrier(0);
        const float* sp = &ring[(k + 1) & (RING - 1)][0];
        f32x4 n0 = *(const f32x4*)(sp + (0 * 4 + grp) * 64 + col * 4);
        f32x4 n1 = *(const f32x4*)(sp + (1 * 4 + grp) * 64 + col * 4);
        f32x4 n2 = *(const f32x4*)(sp + (2 * 4 + grp) * 64 + col * 4);

        // stage slot k+PFS-1
        {
            float* dst = &ring[(k + PFS - 1) & (RING - 1)][0];
#pragma unroll
            for (int s = 0; s < 12; ++s) {
                load_lds4(gbase + soff[s], dst + s * 64);
                soff[s] = BWD ? max(soff[s] - TT * 4, smin[s]) : soff[s] + TT * 4;
            }
        }

        const bf16x4 B0 = bits_to_bf(st[0], st[1]);
        const bf16x4 B1 = bits_to_bf(st[2], st[3]);
        const bf16x4 B2 = bits_to_bf(st[4], st[5]);
        f32x4 a0 = mfma16(A[0][0], B0, kZ);
        f32x4 a1 = mfma16(A[1][0], B0, kZ);
        f32x4 a2 = mfma16(A[2][0], B0, kZ);
        a0 = mfma16(A[0][1], B1, a0);
        a1 = mfma16(A[1][1], B1, a1);
        a2 = mfma16(A[2][1], B1, a2);
        a0 = mfma16(A[0][2], B2, a0);
        a1 = mfma16(A[1][2], B2, a1);
        a2 = mfma16(A[2][2], B2, a2);

        const f32x4 p0 = a0 * e0, p1 = a1 * e1, p2 = a2 * e2;

        const bool live = (k < ns_eff);
        unsigned int w;
        w = cvtpk(p0.x, p0.y); st[0] = live ? w : st[0];
        w = cvtpk(p0.z, p0.w); st[1] = live ? w : st[1];
        w = cvtpk(p1.x, p1.y); st[2] = live ? w : st[2];
        w = cvtpk(p1.z, p1.w); st[3] = live ? w : st[3];
        w = cvtpk(p2.x, p2.y); st[4] = live ? w : st[4];
        w = cvtpk(p2.z, p2.w); st[5] = live ? w : st[5];
        moff2 = live ? (moff2 - shApp) : moff2;

        float sh = 0.f;
        if (k & 1) {   // per-column exact pow2 rescale, every 2 steps
            float cm = fmaxf(fmaxf(fmaxf(p0.x, p0.y), fmaxf(p0.z, p0.w)),
                       fmaxf(fmaxf(fmaxf(p1.x, p1.y), fmaxf(p1.z, p1.w)),
                             fmaxf(fmaxf(p2.x, p2.y), fmaxf(p2.z, p2.w))));
            cm = fmaxf(cm, __shfl_xor(cm, 16));
            cm = fmaxf(cm, __shfl_xor(cm, 32));
            sh = (cm > UP_THR) ? -64.f : ((cm < DN_THR) ? 64.f : 0.f);
        }
        // elg for iter k+1 (shift folded into the exponent: free rescale)
#pragma unroll
        for (int j = 0; j < 4; ++j) {
            e0[j] = __expf(fmaf(sh, LN2F, n0[j]));
            e1[j] = __expf(fmaf(sh, LN2F, n1[j]));
            e2[j] = __expf(fmaf(sh, LN2F, n2[j]));
        }
        shApp = sh;
    }

    // epilogue: unpack, normalize, write
    float fv[12];
#pragma unroll
    for (int C = 0; C < 3; ++C) {
        fv[4 * C + 0] = __uint_as_float(st[2 * C] << 16);
        fv[4 * C + 1] = __uint_as_float(st[2 * C] & 0xffff0000u);
        fv[4 * C + 2] = __uint_as_float(st[2 * C + 1] << 16);
        fv[4 * C + 3] = __uint_as_float(st[2 * C + 1] & 0xffff0000u);
    }
    float cm = fv[0];
#pragma unroll
    for (int i = 1; i < 12; ++i) cm = fmaxf(cm, fv[i]);
    cm = fmaxf(cm, __shfl_xor(cm, 16));
    cm = fmaxf(cm, __shfl_xor(cm, 32));
    const float r = 1.0f / cm;
#pragma unroll
    for (int C = 0; C < 3; ++C)
#pragma unroll
        for (int j = 0; j < 4; ++j)
            vec_out[(size_t)b * 64 + 16 * C + 4 * grp + j] = fv[4 * C + j] * r;
    if (grp == 0) sc_out[b] = moff2 * LN2F + logf(cm);
}

// ---------------- fused kernel: wave0 = chain, wave1 = gold-path score ------
__global__ __launch_bounds__(128) void crf_chain(
    const float* __restrict__ logits, const float* __restrict__ trans,
    const int* __restrict__ labels, const int* __restrict__ lens,
    float* __restrict__ fvec, float* __restrict__ xvec,
    float* __restrict__ fs, float* __restrict__ bs,
    float* __restrict__ scp)
{
    __shared__ __align__(16) float ring[RING][12 * 64];   // 24 KB
    const int g   = blockIdx.x >> 1;
    const int dir = blockIdx.x & 1;
    const int tid = threadIdx.x;
    if (tid < 64) {
        if (dir) run_chain<true >(g, tid, logits, trans, lens, xvec, bs, ring);
        else     run_chain<false>(g, tid, logits, trans, lens, fvec, fs, ring);
    } else {
        const int lane = tid - 64;
        const int seq = lane & 15, part = lane >> 4;
        const int b = g * 16 + seq;
        const int len = lens[b], mid = len >> 1;
        const int lo = dir ? mid : 0;
        const int hi = dir ? len : mid;
        float acc = 0.f;
        for (int t = lo + part; t < hi; t += 4) {
            const int lab = labels[b * LL + t];
            acc += logits[((size_t)(b * LL + t)) * TT + lab];
            const int prev = (t == 0) ? START_TAG : labels[b * LL + t - 1];
            acc += trans[lab * TT + prev];
            if (t == len - 1) acc += trans[STOP_TAG * TT + lab];
        }
        acc += __shfl_xor(acc, 16);
        acc += __shfl_xor(acc, 32);
        if (part == 0) scp[dir * BB + b] = acc;
    }
}

// ---------------- combine: partition - score per sequence --------------------
__global__ __launch_bounds__(64) void crf_combine(
    const float* __restrict__ logits, const float* __restrict__ trans,
    const int* __restrict__ lens,
    const float* __restrict__ fvec, const float* __restrict__ xvec,
    const float* __restrict__ fs, const float* __restrict__ bs,
    const float* __restrict__ scp, float* __restrict__ nll)
{
    const int b = blockIdx.x, lane = threadIdx.x;
    const int len = lens[b], mid = len >> 1;
    float part;
    if (len == 1) {
        float v = -3.0e38f;
        if (lane < TT)
            v = logits[(size_t)b * LL * TT + lane]
              + trans[lane * TT + START_TAG] + trans[STOP_TAG * TT + lane];
        float m = v;
#pragma unroll
        for (int o = 1; o < 64; o <<= 1) m = fmaxf(m, __shfl_xor(m, o));
        float s = __expf(v - m);
#pragma unroll
        for (int o = 1; o < 64; o <<= 1) s += __shfl_xor(s, o);
        part = m + logf(s);
    } else {
        float w = 0.f;
        if (lane < 48)
            w = fvec[(size_t)b * 64 + lane] * xvec[(size_t)b * 64 + lane]
              * __expf(-logits[((size_t)(b * LL + mid - 1)) * TT + lane]);
#pragma unroll
        for (int o = 1; o < 64; o <<= 1) w += __shfl_xor(w, o);
        part = logf(w) + fs[b] + bs[b];
    }
    if (lane == 0) nll[b] = part - scp[b] - scp[BB + b];
}

// ---------------- final deterministic reduction ------------------------------
__global__ __launch_bounds__(1024) void crf_reduce(
    const float* __restrict__ nll, float* __restrict__ out)
{
    __shared__ float red[16];
    const int tid = threadIdx.x;
    float acc = nll[tid];
#pragma unroll
    for (int o = 32; o > 0; o >>= 1) acc += __shfl_xor(acc, o);
    if ((tid & 63) == 0) red[tid >> 6] = acc;
    __syncthreads();
    if (tid == 0) {
        float tot = 0.0f;
        for (int i = 0; i < 16; ++i) tot += red[i];
        out[0] = tot / (float)BB;
    }
}

extern "C" void kernel_launch(void* const* d_in, const int* in_sizes, int n_in,
                              void* d_out, int out_size, void* d_ws, size_t ws_size,
                              hipStream_t stream) {
    const float* logits = (const float*)d_in[0];
    const float* trans  = (const float*)d_in[1];
    const int*   labels = (const int*)d_in[2];
    const int*   lens   = (const int*)d_in[3];

    float* fvec = (float*)d_ws;           // [1024][64]
    float* xvec = fvec + BB * 64;         // [1024][64]
    float* fs   = xvec + BB * 64;         // [1024]
    float* bs   = fs + BB;                // [1024]
    float* scp  = bs + BB;                // [2][1024]
    float* nll  = scp + 2 * BB;           // [1024]
    float* out  = (float*)d_out;

    crf_chain<<<128, 128, 0, stream>>>(logits, trans, labels, lens,
                                       fvec, xvec, fs, bs, scp);
    crf_combine<<<BB, 64, 0, stream>>>(logits, trans, lens,
                                       fvec, xvec, fs, bs, scp, nll);
    crf_reduce<<<1, 1024, 0, stream>>>(nll, out);
}